// Round 10
// baseline (7819.711 us; speedup 1.0000x reference)
//
#include <hip/hip_runtime.h>
#include <math.h>

// FISTA compressed-sensing loop, fused: ONE kernel runs all 200 iterations,
// one 512-thread block per batch image (images are independent; the only
// barrier needed is within-image -> __syncthreads).
//
// R10 rationale: R9 (2 kernels/iter, PASS, 4708 us) was launch-bound:
// ~6 us/iter of compute vs ~17 us/iter of dispatch overhead (400 graph
// nodes). Fusing to 1 dispatch removes that. Y and A stay in GLOBAL d_ws at
// R9's exact addresses (no LDS -> avoids the R2-R5 VGPR-84 spill trap);
// same-CU L1 + __syncthreads' vmcnt-drain gives intra-block coherence
// (__threadfence_block added for the formal model). Stage bodies are R9's
// proven straight-line code verbatim; only the thread->work mapping loops
// changed (no lambdas / register rotation — the R6-R8 failure class).
// W_A layout transposed to [slot][p] (lane-stride-1, 256 B/instr vs 768) —
// pure permutation, halves the L1 weight stream in fused mode.
//
// Phase decomposition (proven R2-R9): ih = 8*qh + ph. A (40x40 s8 SAME) =
// sum over 64 phases of 5x5 convs on the 9x9 grid. At (k=5 s8 SAME, jax pads
// (4,7)): out[8q+rh] (rh<=4) reads only r[q] with w_ct[4-rh][4-rw] ->
// elementwise; zero-filled Wct handles rh/rw>=5 branch-free.
//
// y layout (phase-minor, d_ws): y[(n*243 + r*27 + wc*3 + ci)*64 + p].

#define ITERS 200
#define NY 995328               // 64*243*64 y elements
#define YOFF 0
#define AOFF 995328             // a[n][oh][ow][co]: 64*243
#define WAOFF 1010880           // W_A: 14400 (layout [slot][p])
#define WCTOFF 1025280          // Wct: 576    (total 1,025,856 floats ~4.1 MB)

template <int CTRL>
__device__ __forceinline__ float dpp_add(float x) {
  int moved = __builtin_amdgcn_update_dpp(0, __float_as_int(x), CTRL, 0xF, 0xF, true);
  return x + __int_as_float(moved);
}
// gfx9 wave64 sum; result valid in lane 63. Proven R2-R9.
__device__ __forceinline__ float wave_sum64_to_lane63(float x) {
  x = dpp_add<0x111>(x);
  x = dpp_add<0x112>(x);
  x = dpp_add<0x114>(x);
  x = dpp_add<0x118>(x);
  x = dpp_add<0x142>(x);
  x = dpp_add<0x143>(x);
  return x;
}

// Init: zero Y, reorder weights. W_A transposed vs R9 (lane-stride-1 reads):
// WA2[((t*3+ci)*3+co)*64 + p] = w_conv[8*th+ph][8*tw+pw][ci][co], t=th*5+tw.
// Wct[((rh*8+rw)*3+c)*3 + ci] = (rh<5 && rw<5) ? w_ct[4-rh][4-rw][ci][c] : 0.
__global__ void k0_init(const float* __restrict__ w_conv,
                        const float* __restrict__ w_ct,
                        float* __restrict__ ws) {
  const int i = blockIdx.x * 256 + threadIdx.x;
  if (i < NY) ws[YOFF + i] = 0.f;
  if (i < 14400) {
    const int p = i % 64;
    const int rest = i / 64;       // (t*3+ci)*3+co
    const int co = rest % 3;
    const int rest2 = rest / 3;
    const int ci = rest2 % 3;
    const int t = rest2 / 3;       // th*5+tw
    const int tw = t % 5;
    const int th = t / 5;
    const int pw = p % 8;
    const int ph = p / 8;
    ws[WAOFF + i] = w_conv[(((8 * th + ph) * 40 + (8 * tw + pw)) * 3 + ci) * 3 + co];
  }
  if (i < 576) {
    const int ci = i % 3;
    const int r1 = i / 3;
    const int c = r1 % 3;
    const int r2 = r1 / 3;
    const int rw = r2 % 8;
    const int rh = r2 / 8;
    float v = 0.f;
    if (rh < 5 && rw < 5) v = w_ct[(((4 - rh) * 5 + (4 - rw)) * 3 + ci) * 3 + c];
    ws[WCTOFF + i] = v;
  }
}

__global__ __launch_bounds__(512) void fista_fused(
    float* __restrict__ ws,
    const float* __restrict__ x, const float* __restrict__ lam,
    const float* __restrict__ b_conv, const float* __restrict__ b_ct,
    float* __restrict__ out) {
  const int tid = threadIdx.x;
  const int n = blockIdx.x;       // one block per image
  const int p = tid & 63;         // lane = phase
  const int widx = tid >> 6;      // 0..7

  float* __restrict__ Y   = ws + YOFF + n * 15552;
  float* __restrict__ A   = ws + AOFF + n * 243;
  const float* __restrict__ WA  = ws + WAOFF;
  const float* __restrict__ WCT = ws + WCTOFF;
  const float lam_n = lam[n];

  float t = 1.0f;
#pragma unroll 1
  for (int iter = 0; iter < ITERS; ++iter) {
    // ========== stage 1: a = A(y) + b_conv; 27 wave-jobs over 8 waves ==========
#pragma unroll 1
    for (int j2 = widx; j2 < 27; j2 += 8) {
      const int co = j2 % 3;
      const int job = j2 / 3;      // 0..8
      const int bh = job / 3;
      const int bw = job - bh * 3;

      float acc[9];
#pragma unroll
      for (int k = 0; k < 9; ++k) acc[k] = 0.f;

#pragma unroll 1
      for (int ci = 0; ci < 3; ++ci) {
        float w[25];
#pragma unroll
        for (int tt = 0; tt < 25; ++tt)
          w[tt] = WA[((tt * 3 + ci) * 3 + co) * 64 + p];

#pragma unroll
        for (int r7 = 0; r7 < 7; ++r7) {
          const int r = 3 * bh - 2 + r7;         // input row on 9x9 grid
          if (r >= 0 && r <= 8) {
            float yrow[7];
#pragma unroll
            for (int k = 0; k < 7; ++k) {
              const int wc = 3 * bw - 2 + k;     // input col
              yrow[k] = (wc >= 0 && wc <= 8)
                            ? Y[(r * 27 + wc * 3 + ci) * 64 + p]
                            : 0.f;
            }
#pragma unroll
            for (int pr = 0; pr < 3; ++pr) {
              const int th = r7 - pr;            // r = 3bh + pr + th - 2
              if (th >= 0 && th <= 4) {
#pragma unroll
                for (int tw = 0; tw < 5; ++tw) {
                  const float wv = w[th * 5 + tw];
#pragma unroll
                  for (int pc = 0; pc < 3; ++pc)
                    acc[pr * 3 + pc] += yrow[pc + tw] * wv;
                }
              }
            }
          }
        }
      }

#pragma unroll
      for (int k = 0; k < 9; ++k) acc[k] = wave_sum64_to_lane63(acc[k]);
      if (p == 63) {
        const float bc = b_conv[co];
#pragma unroll
        for (int k = 0; k < 9; ++k) {
          const int oh = 3 * bh + k / 3;
          const int ow = 3 * bw + k % 3;
          A[oh * 27 + ow * 3 + co] = acc[k] + bc;
        }
      }
    }
    __threadfence_block();
    __syncthreads();

    const float tn = (1.0f + sqrtf(1.0f + 4.0f * t * t)) * 0.5f;
    const float beta = (t - 1.0f) / tn;          // beta_0 = 0 (poison-safe ylast)
    t = tn;

    // ========== stage 2: elementwise; 15552 elements over 512 threads ==========
    const bool lastit = (iter == ITERS - 1);
#pragma unroll 1
    for (int e = tid; e < 15552; e += 512) {
      const int ep = e & 63;       // phase = part*8 + rw
      const int q = e >> 6;        // pixel*3+c packed: qh*27+qw*3+c
      const int qh = q / 27;
      const int qr = q - qh * 27;
      const int qw = qr / 3;
      const int c = qr - qw * 3;
      const int part = ep >> 3;
      const int rw = ep & 7;

      const float a0 = A[qh * 27 + qw * 3 + 0];
      const float a1 = A[qh * 27 + qw * 3 + 1];
      const float a2 = A[qh * 27 + qw * 3 + 2];
      const float r0 = x[(n * 81 + qh * 9 + qw) * 3 + 0] - a0;
      const float r1 = x[(n * 81 + qh * 9 + qw) * 3 + 1] - a1;
      const float r2v = x[(n * 81 + qh * 9 + qw) * 3 + 2] - a2;

      const float* wp = WCT + (ep * 3 + c) * 3;
      const float re = b_ct[c] + r0 * wp[0] + r1 * wp[1] + r2v * wp[2];

      const float yt = Y[e];
      const float wv = yt - re;
      const float yn = fmaxf(wv - lam_n, 0.f) - fmaxf(-wv - lam_n, 0.f);

      if (!lastit) {
        const float yl = out[n * 15552 + e];     // ylast scratch in d_out
        out[n * 15552 + e] = yn;
        Y[e] = yn + beta * (yn - yl);
      } else {
        const int ih = 8 * qh + part;
        const int iw = 8 * qw + rw;
        out[((n * 72 + ih) * 72 + iw) * 3 + c] = yn;
      }
    }
    __threadfence_block();
    __syncthreads();
  }
}

extern "C" void kernel_launch(void* const* d_in, const int* in_sizes, int n_in,
                              void* d_out, int out_size, void* d_ws, size_t ws_size,
                              hipStream_t stream) {
  const float* x      = (const float*)d_in[0];
  const float* lam    = (const float*)d_in[1];
  const float* w_conv = (const float*)d_in[2];
  const float* b_conv = (const float*)d_in[3];
  const float* w_ct   = (const float*)d_in[4];
  const float* b_ct   = (const float*)d_in[5];
  float* out = (float*)d_out;
  float* ws  = (float*)d_ws;  // ~4.11 MB

  hipLaunchKernelGGL(k0_init, dim3(3888), dim3(256), 0, stream, w_conv, w_ct, ws);
  hipLaunchKernelGGL(fista_fused, dim3(64), dim3(512), 0, stream,
                     ws, x, lam, b_conv, b_ct, out);
}

// Round 11
// 6204.577 us; speedup vs baseline: 1.2603x; 1.2603x over previous
//
#include <hip/hip_runtime.h>
#include <math.h>

// FISTA compressed-sensing loop, fused: ONE kernel, 200 iterations, one
// 512-thread block per batch image; Y and A in LDS (63,180 B static).
//
// R11 rationale: R10 (global Y/A, PASS, 7.8 ms = 39 us/iter) was bound by
// global-load address VALU (~4 ops/load x ~6k loads/iter -> VALUBusy 56% on
// active CUs) and L1/L2 latency with only 8 waves. LDS swap: ds_read folds
// (r*27+wc*3+ci)*64 into the offset IMMEDIATE (addr math ~1 op/job) and
// ~6 cy LDS replaces ~100-200 cy L1/L2. Storage swap ONLY — R10's proven
// bodies/mapping are byte-identical otherwise.
// VGPR trap check (R2-R5): 512 thr (8 waves) + 63 KB -> 2 WG/CU -> 4
// waves/EU -> 128-reg budget >> 52 live (R10 measured). No spill expected.
// Bank check: lane i hits bank i%32 -> 2-way aliasing = free (m136).
//
// Phase decomposition (proven R2-R10): ih = 8*qh + ph. A (40x40 s8 SAME) =
// sum over 64 phases of 5x5 convs on the 9x9 grid. At (k=5 s8 SAME, jax
// pads (4,7)): out[8q+rh] (rh<=4) reads only r[q] with w_ct[4-rh][4-rw] ->
// elementwise; zero-filled Wct handles rh/rw>=5 branch-free.
//
// y layout (phase-minor, LDS): y[(r*27 + wc*3 + ci)*64 + p], p = ph*8+pw.

#define ITERS 200
#define SA 15552                 // A offset in LDS floats (Y is 0..15551)
#define SMEM_FLOATS 15795        // 63,180 B
#define WAOFF 0                  // d_ws: W_A 14400 floats (layout [slot][p])
#define WCTOFF 14400             // d_ws: Wct 576 floats

template <int CTRL>
__device__ __forceinline__ float dpp_add(float x) {
  int moved = __builtin_amdgcn_update_dpp(0, __float_as_int(x), CTRL, 0xF, 0xF, true);
  return x + __int_as_float(moved);
}
// gfx9 wave64 sum; result valid in lane 63. Proven R2-R10.
__device__ __forceinline__ float wave_sum64_to_lane63(float x) {
  x = dpp_add<0x111>(x);
  x = dpp_add<0x112>(x);
  x = dpp_add<0x114>(x);
  x = dpp_add<0x118>(x);
  x = dpp_add<0x142>(x);
  x = dpp_add<0x143>(x);
  return x;
}

// Weight reorder (R10-proven):
// WA[((t*3+ci)*3+co)*64 + p] = w_conv[8*th+ph][8*tw+pw][ci][co], t=th*5+tw.
// Wct[((rh*8+rw)*3+c)*3 + ci] = (rh<5 && rw<5) ? w_ct[4-rh][4-rw][ci][c] : 0.
__global__ void k0_init(const float* __restrict__ w_conv,
                        const float* __restrict__ w_ct,
                        float* __restrict__ ws) {
  const int i = blockIdx.x * 256 + threadIdx.x;
  if (i < 14400) {
    const int p = i % 64;
    const int rest = i / 64;       // (t*3+ci)*3+co
    const int co = rest % 3;
    const int rest2 = rest / 3;
    const int ci = rest2 % 3;
    const int t = rest2 / 3;       // th*5+tw
    const int tw = t % 5;
    const int th = t / 5;
    const int pw = p % 8;
    const int ph = p / 8;
    ws[WAOFF + i] = w_conv[(((8 * th + ph) * 40 + (8 * tw + pw)) * 3 + ci) * 3 + co];
  }
  if (i < 576) {
    const int ci = i % 3;
    const int r1 = i / 3;
    const int c = r1 % 3;
    const int r2 = r1 / 3;
    const int rw = r2 % 8;
    const int rh = r2 / 8;
    float v = 0.f;
    if (rh < 5 && rw < 5) v = w_ct[(((4 - rh) * 5 + (4 - rw)) * 3 + ci) * 3 + c];
    ws[WCTOFF + i] = v;
  }
}

__global__ __launch_bounds__(512) void fista_fused(
    const float* __restrict__ ws,
    const float* __restrict__ x, const float* __restrict__ lam,
    const float* __restrict__ b_conv, const float* __restrict__ b_ct,
    float* __restrict__ out) {
  __shared__ float smem[SMEM_FLOATS];
  const int tid = threadIdx.x;
  const int n = blockIdx.x;       // one block per image
  const int p = tid & 63;         // lane = phase
  const int widx = tid >> 6;      // 0..7

  const float* __restrict__ WA  = ws + WAOFF;
  const float* __restrict__ WCT = ws + WCTOFF;
  const float lam_n = lam[n];

  // zero Y + A (iter-0 y_tmp = 0)
  for (int i = tid; i < SMEM_FLOATS; i += 512) smem[i] = 0.f;
  __syncthreads();

  float t = 1.0f;
#pragma unroll 1
  for (int iter = 0; iter < ITERS; ++iter) {
    // ========== stage 1: a = A(y) + b_conv; 27 wave-jobs over 8 waves ==========
#pragma unroll 1
    for (int j2 = widx; j2 < 27; j2 += 8) {
      const int co = j2 % 3;
      const int job = j2 / 3;      // 0..8
      const int bh = job / 3;
      const int bw = job - bh * 3;

      float acc[9];
#pragma unroll
      for (int k = 0; k < 9; ++k) acc[k] = 0.f;

#pragma unroll 1
      for (int ci = 0; ci < 3; ++ci) {
        float w[25];
#pragma unroll
        for (int tt = 0; tt < 25; ++tt)
          w[tt] = WA[((tt * 3 + ci) * 3 + co) * 64 + p];

#pragma unroll
        for (int r7 = 0; r7 < 7; ++r7) {
          const int r = 3 * bh - 2 + r7;         // input row on 9x9 grid
          if (r >= 0 && r <= 8) {
            float yrow[7];
#pragma unroll
            for (int k = 0; k < 7; ++k) {
              const int wc = 3 * bw - 2 + k;     // input col
              yrow[k] = (wc >= 0 && wc <= 8)
                            ? smem[(r * 27 + wc * 3 + ci) * 64 + p]
                            : 0.f;
            }
#pragma unroll
            for (int pr = 0; pr < 3; ++pr) {
              const int th = r7 - pr;            // r = 3bh + pr + th - 2
              if (th >= 0 && th <= 4) {
#pragma unroll
                for (int tw = 0; tw < 5; ++tw) {
                  const float wv = w[th * 5 + tw];
#pragma unroll
                  for (int pc = 0; pc < 3; ++pc)
                    acc[pr * 3 + pc] += yrow[pc + tw] * wv;
                }
              }
            }
          }
        }
      }

#pragma unroll
      for (int k = 0; k < 9; ++k) acc[k] = wave_sum64_to_lane63(acc[k]);
      if (p == 63) {
        const float bc = b_conv[co];
#pragma unroll
        for (int k = 0; k < 9; ++k) {
          const int oh = 3 * bh + k / 3;
          const int ow = 3 * bw + k % 3;
          smem[SA + oh * 27 + ow * 3 + co] = acc[k] + bc;
        }
      }
    }
    __syncthreads();

    const float tn = (1.0f + sqrtf(1.0f + 4.0f * t * t)) * 0.5f;
    const float beta = (t - 1.0f) / tn;          // beta_0 = 0 (poison-safe ylast)
    t = tn;

    // ========== stage 2: elementwise; 15552 elements over 512 threads ==========
    const bool lastit = (iter == ITERS - 1);
#pragma unroll 1
    for (int e = tid; e < 15552; e += 512) {
      const int ep = e & 63;       // phase = part*8 + rw
      const int q = e >> 6;        // qh*27 + qw*3 + c
      const int qh = q / 27;
      const int qr = q - qh * 27;
      const int qw = qr / 3;
      const int c = qr - qw * 3;
      const int part = ep >> 3;
      const int rw = ep & 7;

      const float a0 = smem[SA + qh * 27 + qw * 3 + 0];
      const float a1 = smem[SA + qh * 27 + qw * 3 + 1];
      const float a2 = smem[SA + qh * 27 + qw * 3 + 2];
      const float r0 = x[(n * 81 + qh * 9 + qw) * 3 + 0] - a0;
      const float r1 = x[(n * 81 + qh * 9 + qw) * 3 + 1] - a1;
      const float r2v = x[(n * 81 + qh * 9 + qw) * 3 + 2] - a2;

      const float* wp = WCT + (ep * 3 + c) * 3;
      const float re = b_ct[c] + r0 * wp[0] + r1 * wp[1] + r2v * wp[2];

      const float yt = smem[e];
      const float wv = yt - re;
      const float yn = fmaxf(wv - lam_n, 0.f) - fmaxf(-wv - lam_n, 0.f);

      if (!lastit) {
        const float yl = out[n * 15552 + e];     // ylast scratch in d_out
        out[n * 15552 + e] = yn;
        smem[e] = yn + beta * (yn - yl);
      } else {
        const int ih = 8 * qh + part;
        const int iw = 8 * qw + rw;
        out[((n * 72 + ih) * 72 + iw) * 3 + c] = yn;
      }
    }
    __syncthreads();
  }
}

extern "C" void kernel_launch(void* const* d_in, const int* in_sizes, int n_in,
                              void* d_out, int out_size, void* d_ws, size_t ws_size,
                              hipStream_t stream) {
  const float* x      = (const float*)d_in[0];
  const float* lam    = (const float*)d_in[1];
  const float* w_conv = (const float*)d_in[2];
  const float* b_conv = (const float*)d_in[3];
  const float* w_ct   = (const float*)d_in[4];
  const float* b_ct   = (const float*)d_in[5];
  float* out = (float*)d_out;
  float* ws  = (float*)d_ws;  // 14,976 floats (~60 KB)

  hipLaunchKernelGGL(k0_init, dim3(57), dim3(256), 0, stream, w_conv, w_ct, ws);
  hipLaunchKernelGGL(fista_fused, dim3(64), dim3(512), 0, stream,
                     ws, x, lam, b_conv, b_ct, out);
}

// Round 12
// 4416.655 us; speedup vs baseline: 1.7705x; 1.4048x over previous
//
#include <hip/hip_runtime.h>
#include <math.h>

// FISTA compressed-sensing loop, fused: ONE kernel, 200 iterations, one
// 1024-thread block per batch image; Y and A in LDS (63,180 B static).
//
// R12 rationale: R11 (512 thr, PASS, 6.2 ms = 31 us/iter) is stall-bound:
// VALUBusy 17% chip = ~68% on the 64 active CUs; pure-issue model says ~9
// us/iter, so ~20 us/iter is latency (25-wide weight batches ~100-200 cy,
// 7-wide ds batches ~120 cy) that 2 waves/SIMD cannot hide, plus the 4/3 job
// imbalance tail at each barrier. Single change: 16 waves (1024 thr) -> 4
// waves/SIMD hiding, job balance 2/1. VGPR check: 63.5 KB LDS -> 2 WG/CU ->
// 8 waves/EU -> budget 512/8 = 64 >= 52 measured live -> no spill expected
// (tripwire: hbm_bytes jump = spills = revert).
//
// Phase decomposition (proven R2-R11): ih = 8*qh + ph. A (40x40 s8 SAME) =
// sum over 64 phases of 5x5 convs on the 9x9 grid. At (k=5 s8 SAME, jax
// pads (4,7)): out[8q+rh] (rh<=4) reads only r[q] with w_ct[4-rh][4-rw] ->
// elementwise; zero-filled Wct handles rh/rw>=5 branch-free.
//
// y layout (phase-minor, LDS): y[(r*27 + wc*3 + ci)*64 + p], p = ph*8+pw.

#define ITERS 200
#define THREADS 1024
#define NWAVES 16
#define SA 15552                 // A offset in LDS floats (Y is 0..15551)
#define SMEM_FLOATS 15795        // 63,180 B
#define WAOFF 0                  // d_ws: W_A 14400 floats (layout [slot][p])
#define WCTOFF 14400             // d_ws: Wct 576 floats

template <int CTRL>
__device__ __forceinline__ float dpp_add(float x) {
  int moved = __builtin_amdgcn_update_dpp(0, __float_as_int(x), CTRL, 0xF, 0xF, true);
  return x + __int_as_float(moved);
}
// gfx9 wave64 sum; result valid in lane 63. Proven R2-R11.
__device__ __forceinline__ float wave_sum64_to_lane63(float x) {
  x = dpp_add<0x111>(x);
  x = dpp_add<0x112>(x);
  x = dpp_add<0x114>(x);
  x = dpp_add<0x118>(x);
  x = dpp_add<0x142>(x);
  x = dpp_add<0x143>(x);
  return x;
}

// Weight reorder (R10-proven):
// WA[((t*3+ci)*3+co)*64 + p] = w_conv[8*th+ph][8*tw+pw][ci][co], t=th*5+tw.
// Wct[((rh*8+rw)*3+c)*3 + ci] = (rh<5 && rw<5) ? w_ct[4-rh][4-rw][ci][c] : 0.
__global__ void k0_init(const float* __restrict__ w_conv,
                        const float* __restrict__ w_ct,
                        float* __restrict__ ws) {
  const int i = blockIdx.x * 256 + threadIdx.x;
  if (i < 14400) {
    const int p = i % 64;
    const int rest = i / 64;       // (t*3+ci)*3+co
    const int co = rest % 3;
    const int rest2 = rest / 3;
    const int ci = rest2 % 3;
    const int t = rest2 / 3;       // th*5+tw
    const int tw = t % 5;
    const int th = t / 5;
    const int pw = p % 8;
    const int ph = p / 8;
    ws[WAOFF + i] = w_conv[(((8 * th + ph) * 40 + (8 * tw + pw)) * 3 + ci) * 3 + co];
  }
  if (i < 576) {
    const int ci = i % 3;
    const int r1 = i / 3;
    const int c = r1 % 3;
    const int r2 = r1 / 3;
    const int rw = r2 % 8;
    const int rh = r2 / 8;
    float v = 0.f;
    if (rh < 5 && rw < 5) v = w_ct[(((4 - rh) * 5 + (4 - rw)) * 3 + ci) * 3 + c];
    ws[WCTOFF + i] = v;
  }
}

__global__ __launch_bounds__(THREADS) void fista_fused(
    const float* __restrict__ ws,
    const float* __restrict__ x, const float* __restrict__ lam,
    const float* __restrict__ b_conv, const float* __restrict__ b_ct,
    float* __restrict__ out) {
  __shared__ float smem[SMEM_FLOATS];
  const int tid = threadIdx.x;
  const int n = blockIdx.x;       // one block per image
  const int p = tid & 63;         // lane = phase
  const int widx = tid >> 6;      // 0..15

  const float* __restrict__ WA  = ws + WAOFF;
  const float* __restrict__ WCT = ws + WCTOFF;
  const float lam_n = lam[n];

  // zero Y + A (iter-0 y_tmp = 0)
  for (int i = tid; i < SMEM_FLOATS; i += THREADS) smem[i] = 0.f;
  __syncthreads();

  float t = 1.0f;
#pragma unroll 1
  for (int iter = 0; iter < ITERS; ++iter) {
    // ========== stage 1: a = A(y) + b_conv; 27 wave-jobs over 16 waves ==========
#pragma unroll 1
    for (int j2 = widx; j2 < 27; j2 += NWAVES) {
      const int co = j2 % 3;
      const int job = j2 / 3;      // 0..8
      const int bh = job / 3;
      const int bw = job - bh * 3;

      float acc[9];
#pragma unroll
      for (int k = 0; k < 9; ++k) acc[k] = 0.f;

#pragma unroll 1
      for (int ci = 0; ci < 3; ++ci) {
        float w[25];
#pragma unroll
        for (int tt = 0; tt < 25; ++tt)
          w[tt] = WA[((tt * 3 + ci) * 3 + co) * 64 + p];

#pragma unroll
        for (int r7 = 0; r7 < 7; ++r7) {
          const int r = 3 * bh - 2 + r7;         // input row on 9x9 grid
          if (r >= 0 && r <= 8) {
            float yrow[7];
#pragma unroll
            for (int k = 0; k < 7; ++k) {
              const int wc = 3 * bw - 2 + k;     // input col
              yrow[k] = (wc >= 0 && wc <= 8)
                            ? smem[(r * 27 + wc * 3 + ci) * 64 + p]
                            : 0.f;
            }
#pragma unroll
            for (int pr = 0; pr < 3; ++pr) {
              const int th = r7 - pr;            // r = 3bh + pr + th - 2
              if (th >= 0 && th <= 4) {
#pragma unroll
                for (int tw = 0; tw < 5; ++tw) {
                  const float wv = w[th * 5 + tw];
#pragma unroll
                  for (int pc = 0; pc < 3; ++pc)
                    acc[pr * 3 + pc] += yrow[pc + tw] * wv;
                }
              }
            }
          }
        }
      }

#pragma unroll
      for (int k = 0; k < 9; ++k) acc[k] = wave_sum64_to_lane63(acc[k]);
      if (p == 63) {
        const float bc = b_conv[co];
#pragma unroll
        for (int k = 0; k < 9; ++k) {
          const int oh = 3 * bh + k / 3;
          const int ow = 3 * bw + k % 3;
          smem[SA + oh * 27 + ow * 3 + co] = acc[k] + bc;
        }
      }
    }
    __syncthreads();

    const float tn = (1.0f + sqrtf(1.0f + 4.0f * t * t)) * 0.5f;
    const float beta = (t - 1.0f) / tn;          // beta_0 = 0 (poison-safe ylast)
    t = tn;

    // ========== stage 2: elementwise; 15552 elements over 1024 threads ==========
    const bool lastit = (iter == ITERS - 1);
#pragma unroll 1
    for (int e = tid; e < 15552; e += THREADS) {
      const int ep = e & 63;       // phase = part*8 + rw
      const int q = e >> 6;        // qh*27 + qw*3 + c
      const int qh = q / 27;
      const int qr = q - qh * 27;
      const int qw = qr / 3;
      const int c = qr - qw * 3;
      const int part = ep >> 3;
      const int rw = ep & 7;

      const float a0 = smem[SA + qh * 27 + qw * 3 + 0];
      const float a1 = smem[SA + qh * 27 + qw * 3 + 1];
      const float a2 = smem[SA + qh * 27 + qw * 3 + 2];
      const float r0 = x[(n * 81 + qh * 9 + qw) * 3 + 0] - a0;
      const float r1 = x[(n * 81 + qh * 9 + qw) * 3 + 1] - a1;
      const float r2v = x[(n * 81 + qh * 9 + qw) * 3 + 2] - a2;

      const float* wp = WCT + (ep * 3 + c) * 3;
      const float re = b_ct[c] + r0 * wp[0] + r1 * wp[1] + r2v * wp[2];

      const float yt = smem[e];
      const float wv = yt - re;
      const float yn = fmaxf(wv - lam_n, 0.f) - fmaxf(-wv - lam_n, 0.f);

      if (!lastit) {
        const float yl = out[n * 15552 + e];     // ylast scratch in d_out
        out[n * 15552 + e] = yn;
        smem[e] = yn + beta * (yn - yl);
      } else {
        const int ih = 8 * qh + part;
        const int iw = 8 * qw + rw;
        out[((n * 72 + ih) * 72 + iw) * 3 + c] = yn;
      }
    }
    __syncthreads();
  }
}

extern "C" void kernel_launch(void* const* d_in, const int* in_sizes, int n_in,
                              void* d_out, int out_size, void* d_ws, size_t ws_size,
                              hipStream_t stream) {
  const float* x      = (const float*)d_in[0];
  const float* lam    = (const float*)d_in[1];
  const float* w_conv = (const float*)d_in[2];
  const float* b_conv = (const float*)d_in[3];
  const float* w_ct   = (const float*)d_in[4];
  const float* b_ct   = (const float*)d_in[5];
  float* out = (float*)d_out;
  float* ws  = (float*)d_ws;  // 14,976 floats (~60 KB)

  hipLaunchKernelGGL(k0_init, dim3(57), dim3(256), 0, stream, w_conv, w_ct, ws);
  hipLaunchKernelGGL(fista_fused, dim3(64), dim3(THREADS), 0, stream,
                     ws, x, lam, b_conv, b_ct, out);
}

// Round 13
// 3440.889 us; speedup vs baseline: 2.2726x; 1.2836x over previous
//
#include <hip/hip_runtime.h>
#include <math.h>

// FISTA compressed-sensing loop, fused: ONE kernel, 200 iterations, one
// 1024-thread block per batch image; Y + ci-partial conv outputs in LDS.
//
// R13 rationale: R12 (4.42 ms, 22 us/iter) is issue-bound on the 64 active
// CUs (VALUBusy ~98% active). Largest modeled pipe: LDS ~26k cy/iter, of
// which stage-1 y-window reads are 3,240 ds_read_b32 because co was split
// across jobs (same window read 3x). Changes:
//  (1) stage-1 job = (oh, ci): full output row, acc[27] (9 ow x 3 co), row
//      regs rv[13] -> each y read ONCE: ~1,050 ds_read/iter (3.1x cut).
//      Live regs ~55 < 64 budget (2WG/CU x 16 waves -> 8 waves/EU -> 64).
//  (2) ci-partials apart[3][243] in LDS (overwritten each iter); pre-pass
//      (threads<243) sums partials + b_conv into apart[0] (alias-safe:
//      thread t reads/writes only index t); stage-2 reads a as before.
//  (3) stage-2 indexed by pix = cell*3+c: Y idx pix*64+p, x idx n*243+pix,
//      a idx pix -> divides nearly gone; NHWC unpack only on final iter.
//
// Phase decomposition (proven R2-R12): ih = 8*qh + ph. A (40x40 s8 SAME) =
// sum over 64 phases of 5x5 convs on the 9x9 grid:
//   a[oh,ow,co] += y[oh+th-2][ow+tw-2][ci] * W[th][tw][ci][co]
// At (k=5 s8 SAME, jax pads (4,7)): out[8q+rh] (rh<=4) reads only r[q] with
// w_ct[4-rh][4-rw] -> elementwise; zero-filled Wct handles rh/rw>=5.
//
// y layout (phase-minor, LDS): y[(r*27 + wc*3 + ci)*64 + p], p = ph*8+pw.

#define ITERS 200
#define THREADS 1024
#define NWAVES 16
#define YN 15552                 // apart offset (Y is 0..15551)
#define SMEM_FLOATS (YN + 729)   // 16,281 floats = 65,124 B <= 64 KiB
#define WAOFF 0                  // d_ws: W_A 14400 floats [((t*3+ci)*3+co)][p]
#define WCTOFF 14400             // d_ws: Wct 576 floats

template <int CTRL>
__device__ __forceinline__ float dpp_add(float x) {
  int moved = __builtin_amdgcn_update_dpp(0, __float_as_int(x), CTRL, 0xF, 0xF, true);
  return x + __int_as_float(moved);
}
// gfx9 wave64 sum; result valid in lane 63. Proven R2-R12.
__device__ __forceinline__ float wave_sum64_to_lane63(float x) {
  x = dpp_add<0x111>(x);
  x = dpp_add<0x112>(x);
  x = dpp_add<0x114>(x);
  x = dpp_add<0x118>(x);
  x = dpp_add<0x142>(x);
  x = dpp_add<0x143>(x);
  return x;
}

// Weight reorder (R10-proven layouts, unchanged):
// WA[((t*3+ci)*3+co)*64 + p] = w_conv[8*th+ph][8*tw+pw][ci][co], t=th*5+tw.
// Wct[((rh*8+rw)*3+c)*3 + ci] = (rh<5 && rw<5) ? w_ct[4-rh][4-rw][ci][c] : 0.
__global__ void k0_init(const float* __restrict__ w_conv,
                        const float* __restrict__ w_ct,
                        float* __restrict__ ws) {
  const int i = blockIdx.x * 256 + threadIdx.x;
  if (i < 14400) {
    const int p = i % 64;
    const int rest = i / 64;       // (t*3+ci)*3+co
    const int co = rest % 3;
    const int rest2 = rest / 3;
    const int ci = rest2 % 3;
    const int t = rest2 / 3;       // th*5+tw
    const int tw = t % 5;
    const int th = t / 5;
    const int pw = p % 8;
    const int ph = p / 8;
    ws[WAOFF + i] = w_conv[(((8 * th + ph) * 40 + (8 * tw + pw)) * 3 + ci) * 3 + co];
  }
  if (i < 576) {
    const int ci = i % 3;
    const int r1 = i / 3;
    const int c = r1 % 3;
    const int r2 = r1 / 3;
    const int rw = r2 % 8;
    const int rh = r2 / 8;
    float v = 0.f;
    if (rh < 5 && rw < 5) v = w_ct[(((4 - rh) * 5 + (4 - rw)) * 3 + ci) * 3 + c];
    ws[WCTOFF + i] = v;
  }
}

__global__ __launch_bounds__(THREADS) void fista_fused(
    const float* __restrict__ ws,
    const float* __restrict__ x, const float* __restrict__ lam,
    const float* __restrict__ b_conv, const float* __restrict__ b_ct,
    float* __restrict__ out) {
  __shared__ float smem[SMEM_FLOATS];
  const int tid = threadIdx.x;
  const int n = blockIdx.x;       // one block per image
  const int p = tid & 63;         // lane = phase
  const int widx = tid >> 6;      // 0..15

  const float* __restrict__ WA  = ws + WAOFF;
  const float* __restrict__ WCT = ws + WCTOFF;
  const float lam_n = lam[n];
  const float bc_pre = (tid < 243) ? b_conv[tid % 3] : 0.f;  // pre-pass bias

  // zero Y (iter-0 y_tmp = 0); apart is written before read every iter
  for (int i = tid; i < SMEM_FLOATS; i += THREADS) smem[i] = 0.f;
  __syncthreads();

  float t = 1.0f;
#pragma unroll 1
  for (int iter = 0; iter < ITERS; ++iter) {
    // ===== stage 1: ci-partial conv; 27 jobs (oh,ci) over 16 waves ============
#pragma unroll 1
    for (int j2 = widx; j2 < 27; j2 += NWAVES) {
      const int ci = j2 / 9;       // 0..2
      const int oh = j2 - ci * 9;  // 0..8

      float acc[27];               // [ow*3 + co]
#pragma unroll
      for (int k = 0; k < 27; ++k) acc[k] = 0.f;

#pragma unroll
      for (int th = 0; th < 5; ++th) {
        const int r = oh + th - 2;          // input row
        if (r >= 0 && r <= 8) {
          float rv[13];                     // y col (k-2), zero-padded
          rv[0] = 0.f; rv[1] = 0.f; rv[11] = 0.f; rv[12] = 0.f;
#pragma unroll
          for (int k = 2; k <= 10; ++k)
            rv[k] = smem[(r * 27 + (k - 2) * 3 + ci) * 64 + p];

#pragma unroll
          for (int tw = 0; tw < 5; ++tw) {
            const int wb = ((th * 5 + tw) * 3 + ci) * 3;
            const float w0 = WA[(wb + 0) * 64 + p];
            const float w1 = WA[(wb + 1) * 64 + p];
            const float w2 = WA[(wb + 2) * 64 + p];
#pragma unroll
            for (int ow = 0; ow < 9; ++ow) {
              const float y = rv[ow + tw];  // col ow+tw-2 -> rv[ow+tw]
              acc[ow * 3 + 0] += y * w0;
              acc[ow * 3 + 1] += y * w1;
              acc[ow * 3 + 2] += y * w2;
            }
          }
        }
      }

#pragma unroll
      for (int k = 0; k < 27; ++k) acc[k] = wave_sum64_to_lane63(acc[k]);
      if (p == 63) {
#pragma unroll
        for (int k = 0; k < 27; ++k)
          smem[YN + ci * 243 + oh * 27 + k] = acc[k];   // apart[ci][oh*27+ow*3+co]
      }
    }
    __syncthreads();

    // ===== pre-pass: a = sum_ci apart + b_conv, into apart[0] (alias-safe) ====
    if (tid < 243) {
      smem[YN + tid] = smem[YN + tid] + smem[YN + 243 + tid] +
                       smem[YN + 486 + tid] + bc_pre;
    }
    __syncthreads();

    const float tn = (1.0f + sqrtf(1.0f + 4.0f * t * t)) * 0.5f;
    const float beta = (t - 1.0f) / tn;          // beta_0 = 0 (poison-safe ylast)
    t = tn;

    // ===== stage 2: elementwise; pix = cell*3+c wave-uniform, lane = p ========
    const bool lastit = (iter == ITERS - 1);
#pragma unroll 1
    for (int m = widx; m < 243; m += NWAVES) {   // m = pix (wave-uniform)
      const int cdiv = m / 3;                    // cell
      const int c = m - 3 * cdiv;
      const int cb = 3 * cdiv;

      const float a0 = smem[YN + cb + 0];
      const float a1 = smem[YN + cb + 1];
      const float a2 = smem[YN + cb + 2];
      const float r0 = x[n * 243 + cb + 0] - a0;
      const float r1 = x[n * 243 + cb + 1] - a1;
      const float r2v = x[n * 243 + cb + 2] - a2;

      const float* wp = WCT + (p * 3 + c) * 3;
      const float re = b_ct[c] + r0 * wp[0] + r1 * wp[1] + r2v * wp[2];

      const int e = m * 64 + p;
      const float yt = smem[e];
      const float wv = yt - re;
      const float yn = fmaxf(wv - lam_n, 0.f) - fmaxf(-wv - lam_n, 0.f);

      if (!lastit) {
        const float yl = out[n * 15552 + e];     // ylast scratch in d_out
        out[n * 15552 + e] = yn;
        smem[e] = yn + beta * (yn - yl);
      } else {
        const int part = p >> 3;
        const int rw = p & 7;
        const int qh = cdiv / 9;
        const int qw = cdiv - 9 * qh;
        const int ih = 8 * qh + part;
        const int iw = 8 * qw + rw;
        out[((n * 72 + ih) * 72 + iw) * 3 + c] = yn;
      }
    }
    __syncthreads();
  }
}

extern "C" void kernel_launch(void* const* d_in, const int* in_sizes, int n_in,
                              void* d_out, int out_size, void* d_ws, size_t ws_size,
                              hipStream_t stream) {
  const float* x      = (const float*)d_in[0];
  const float* lam    = (const float*)d_in[1];
  const float* w_conv = (const float*)d_in[2];
  const float* b_conv = (const float*)d_in[3];
  const float* w_ct   = (const float*)d_in[4];
  const float* b_ct   = (const float*)d_in[5];
  float* out = (float*)d_out;
  float* ws  = (float*)d_ws;  // 14,976 floats (~60 KB)

  hipLaunchKernelGGL(k0_init, dim3(57), dim3(256), 0, stream, w_conv, w_ct, ws);
  hipLaunchKernelGGL(fista_fused, dim3(64), dim3(THREADS), 0, stream,
                     ws, x, lam, b_conv, b_ct, out);
}